// Round 12
// baseline (21612.314 us; speedup 1.0000x reference)
//
#include <hip/hip_runtime.h>

// LayerNorm-LSTM, S=512 B=64 I=H=512 L=2, all I/O f32, all compute f32
// (recurrence is chaotic: bf16 anywhere => absmax ~1.4 FAIL; f32 ordering
//  noise => ~0.016 PASS. f32 VALU only, deterministic reduction orders.)
//
// Persistent kernel: 256 WGs x 256 thr, 1 WG/CU. W slice (64 KB) in LDS.
//   wg = [layer(2)][w(128)]; WG owns rows 0..63 x hc [4w,4w+4) x 4 gates.
//   Per tick: 1024 outputs = [x_t;h](64x1024) @ Wslice(1024x16).
//
// Sync evolution: grid.sync 45us/call (R8, 49ms); contended counter (R9,
// 58ms); flag-array + agent fences (R10, 34.6ms); 3 fence-light rounds
// (R11, 20.3ms). R12: 2 rounds/tick, ZERO cache fences:
//  - every cross-WG datum (h, y0 via out[t], slots) moves via SYSTEM-scope
//    u64 atomics (bypass L1/L2 both sides -> coherent without fences; the
//    R11-proven path). L0's x-half reads immutable `inputs` cached.
//  - minv round deleted: each WG redundantly reduces ALL 256 (row,gate)
//    slot pairs (transposed [slice][pair] layout, coalesced; deterministic
//    8-chain sum order identical in every WG).
//  - flags: phase 2t+1 = slots posted, 2t+2 = h/y0 posted. Slots round
//    orders all y0/h reads before overwrites (R8-R11 invariant).

#define NTH 256

typedef float f32x4 __attribute__((ext_vector_type(4)));

__device__ __forceinline__ float sigm(float x) { return 1.f / (1.f + __expf(-x)); }
__device__ __forceinline__ float tanh_f(float x) { return 2.f / (1.f + __expf(-2.f * x)) - 1.f; }

__device__ __forceinline__ unsigned long long pack2(float a, float b) {
  union { float f[2]; unsigned long long u; } x; x.f[0] = a; x.f[1] = b; return x.u;
}
__device__ __forceinline__ float lo2(unsigned long long u) {
  union { unsigned long long u; float f[2]; } x; x.u = u; return x.f[0];
}
__device__ __forceinline__ float hi2(unsigned long long u) {
  union { unsigned long long u; float f[2]; } x; x.u = u; return x.f[1];
}
__device__ __forceinline__ void sys_store64(unsigned long long* p, unsigned long long v) {
  __hip_atomic_store(p, v, __ATOMIC_RELAXED, __HIP_MEMORY_SCOPE_SYSTEM);
}
__device__ __forceinline__ unsigned long long sys_load64(const unsigned long long* p) {
  return __hip_atomic_load(p, __ATOMIC_RELAXED, __HIP_MEMORY_SCOPE_SYSTEM);
}

// post: __syncthreads drains all threads' prior stores (compiler emits
// vmcnt(0) before s_barrier), then single-writer RELEASE phase store.
__device__ __forceinline__ void post(unsigned int* flag, unsigned int val) {
  __syncthreads();
  if (threadIdx.x == 0)
    __hip_atomic_store(flag, val, __ATOMIC_RELEASE, __HIP_MEMORY_SCOPE_SYSTEM);
}

// waitall: until flags[i*32] >= target for all i<128. Data read afterwards
// is SYSTEM-scope (uncached) -> no hardware cache fence needed.
__device__ __forceinline__ void waitall(const unsigned int* flags, unsigned int target) {
  long guard = 0;
  for (;;) {
    int ok = 1;
    if (threadIdx.x < 128) {
      unsigned int v = __hip_atomic_load(&flags[threadIdx.x * 32],
                                         __ATOMIC_RELAXED, __HIP_MEMORY_SCOPE_SYSTEM);
      ok = (v >= target);
    }
    if (__syncthreads_and(ok)) break;
    if (++guard > (1L << 22)) break;   // safety valve; never hit when healthy
  }
  __atomic_signal_fence(__ATOMIC_ACQUIRE);
}

__global__ __launch_bounds__(NTH, 1)
void lstm_pk(const float* __restrict__ inputs, const float* __restrict__ h0,
             const float* __restrict__ c0,
             const float* __restrict__ wx0, const float* __restrict__ wx1,
             const float* __restrict__ wh0, const float* __restrict__ wh1,
             const float* __restrict__ bias, const float* __restrict__ gamma_,
             const float* __restrict__ beta_,
             float* __restrict__ out,
             unsigned int* flags,               // [2][128][32] u32
             unsigned long long* slots,         // [2][128 slice][256 pair] u64
             float* __restrict__ h_state)       // [2][64][512] f32
{
  extern __shared__ float lds[];
  float* W_lds = lds;                   // [1024][16]        16384 f = 64 KB
  float* A_lds = lds + 16384;           // [2][128][68]      17408 f = 68 KB
  float* part  = lds + 16384 + 17408;   // [4][64][17]        4352 f = 17 KB
  float* gates = part + 4352;           // [64][16]           1024 f =  4 KB
  float* minv  = gates + 1024;          // [256 pair][2]       512 f =  2 KB
  // total 39680 floats = 158720 B

  const int tid = threadIdx.x;
  const int wg = blockIdx.x;
  const int layer = wg >> 7;
  const int w = wg & 127;            // hc slice [4w, 4w+4)
  const int wavet = tid >> 6;        // K-split group 0..3
  const int lane = tid & 63;
  const int rq = lane & 15;          // row quad -> rows 4rq..4rq+3
  const int gq = lane >> 4;          // gate (col quad)
  const int srow = tid >> 2;         // stats/cell row 0..63
  const int sg = tid & 3;            // stats gate / cell hc-within-slice
  const int hc = 4 * w + sg;         // global h column (cell phase)

  const float* Wx = layer ? wx1 : wx0;
  const float* Wh = layer ? wh1 : wh0;

  // ---- one-time: W slice -> LDS. W_lds[k][g*4+j] = W[k][g*512+4w+j]
  for (int i = 0; i < 16; ++i) {
    int e = tid + i * 256;           // [0,4096)
    int k = e >> 2, g = e & 3;
    const float* src = (k < 512) ? (Wx + (size_t)k * 2048)
                                 : (Wh + (size_t)(k - 512) * 2048);
    f32x4 v = *(const f32x4*)(src + g * 512 + 4 * w);
    *(f32x4*)&W_lds[k * 16 + g * 4] = v;
  }

  f32x4 biasr = *(const f32x4*)(bias + layer * 2048 + sg * 512 + 4 * w);
  float gam[4], bet[4];
#pragma unroll
  for (int g = 0; g < 4; ++g) {
    gam[g] = gamma_[layer * 2048 + g * 512 + hc];
    bet[g] = beta_[layer * 2048 + g * 512 + hc];
  }
  float c_st = c0[layer * 32768 + srow * 512 + hc];

  unsigned long long* slotL = slots + (size_t)layer * 32768;  // [128][256]
  float* hstL = h_state + layer * 32768;
  unsigned int* fmyL = flags + layer * 4096;     // my layer's 128 flags
  unsigned int* myflag = fmyL + w * 32;
  const unsigned int* fL0 = flags;               // layer-0 flags

  const int strow = rq + 16 * wavet;             // staging row for this thread
  const int first = layer ? 4 : 0;               // L1: h-half first

  for (int t = 0; t < 512; ++t) {
    const unsigned int t2 = 2u * (unsigned)t;
    const float* xsrc = (layer ? out : inputs) + (size_t)t * 32768;
    const float* hsrc = (t == 0) ? (h0 + layer * 32768) : hstL;

    // L1 starts with the h-half: own h(t-1) must be posted.
    if (layer == 1 && t > 0) waitall(fmyL, t2);

    f32x4 acc[4];
#pragma unroll
    for (int r = 0; r < 4; ++r) acc[r] = (f32x4){0.f, 0.f, 0.f, 0.f};

    f32x4 st[8];
    auto LOADC = [&](int c) {            // chunk c: c>=4 -> h, else x
      const int koff = (c & 3) * 128;
      if (c < 4 && layer == 0) {         // immutable inputs: cached f32x4
        const float* src = xsrc + strow * 512 + koff;
#pragma unroll
        for (int i = 0; i < 8; ++i) {
          int kq = gq + 4 * i;
          st[i] = *(const f32x4*)(src + 4 * kq);
        }
      } else {                           // produced data: SYSTEM u64 loads
        const float* src = ((c >= 4) ? hsrc : xsrc) + strow * 512 + koff;
        const unsigned long long* s64 = (const unsigned long long*)src;
#pragma unroll
        for (int i = 0; i < 8; ++i) {
          int kq = gq + 4 * i;
          unsigned long long a = sys_load64(&s64[2 * kq]);
          unsigned long long b = sys_load64(&s64[2 * kq + 1]);
          st[i][0] = lo2(a); st[i][1] = hi2(a);
          st[i][2] = lo2(b); st[i][3] = hi2(b);
        }
      }
    };
    auto WRITEC = [&](int b) {           // regs -> A_lds[b], [k][row]
      float* dst = A_lds + b * 8704;
#pragma unroll
      for (int i = 0; i < 8; ++i) {
        int kq = gq + 4 * i;
#pragma unroll
        for (int j = 0; j < 4; ++j)
          dst[(4 * kq + j) * 68 + strow] = st[i][j];
      }
    };
    auto COMPUTEC = [&](int c, int b) {
      const float* Ab = A_lds + b * 8704;
      const int kg = c * 128 + wavet * 32;
#pragma unroll 8
      for (int kk = 0; kk < 32; ++kk) {
        int k = wavet * 32 + kk;
        f32x4 av = *(const f32x4*)&Ab[k * 68 + 4 * rq];
        f32x4 wv = *(const f32x4*)&W_lds[(kg + kk) * 16 + gq * 4];
        acc[0] += av[0] * wv;
        acc[1] += av[1] * wv;
        acc[2] += av[2] * wv;
        acc[3] += av[3] * wv;
      }
    };

    LOADC(first);
    WRITEC(0);
    __syncthreads();
#pragma unroll 1
    for (int co = 0; co < 8; ++co) {
      int c = (co + first) & 7;
      if (co < 7) {
        if (co == 3) {
          // about to prefetch the other half's first chunk
          if (layer == 1) waitall(fL0, t2 + 2u);       // y0(t) posted by L0
          else if (t > 0) waitall(fmyL, t2);           // own h(t-1) posted
        }
        LOADC((c + 1) & 7);
      }
      COMPUTEC(c, co & 1);
      if (co < 7) WRITEC((co + 1) & 1);
      __syncthreads();
    }

    // partials -> LDS (part[m][row][g*4+c], pad 17)
#pragma unroll
    for (int r = 0; r < 4; ++r)
#pragma unroll
      for (int cc = 0; cc < 4; ++cc)
        part[(wavet * 64 + 4 * rq + r) * 17 + gq * 4 + cc] = acc[r][cc];
    __syncthreads();

    // sum 4 K-groups + bias -> gates LDS; stats partial -> slot (SYSTEM)
    {
      f32x4 pre;
#pragma unroll
      for (int cc = 0; cc < 4; ++cc) {
        float v = biasr[cc];
        v += part[(0 * 64 + srow) * 17 + sg * 4 + cc];
        v += part[(1 * 64 + srow) * 17 + sg * 4 + cc];
        v += part[(2 * 64 + srow) * 17 + sg * 4 + cc];
        v += part[(3 * 64 + srow) * 17 + sg * 4 + cc];
        pre[cc] = v;
      }
      *(f32x4*)&gates[srow * 16 + sg * 4] = pre;
      float s = ((pre[0] + pre[1]) + pre[2]) + pre[3];
      float ss = ((pre[0] * pre[0] + pre[1] * pre[1]) + pre[2] * pre[2]) + pre[3] * pre[3];
      sys_store64(&slotL[(size_t)w * 256 + tid], pack2(s, ss));  // [slice][pair]
    }
    post(myflag, t2 + 1u);               // slots posted
    waitall(fmyL, t2 + 1u);

    // redundant deterministic reduce: this thread owns pair p=tid.
    // 8 independent chains over the 128 slices, fixed combine order.
    {
      float Sc[8], SSc[8];
#pragma unroll
      for (int j = 0; j < 8; ++j) { Sc[j] = 0.f; SSc[j] = 0.f; }
#pragma unroll 4
      for (int q8 = 0; q8 < 16; ++q8) {
#pragma unroll
        for (int j = 0; j < 8; ++j) {
          unsigned long long u = sys_load64(&slotL[(size_t)(q8 * 8 + j) * 256 + tid]);
          Sc[j] += lo2(u); SSc[j] += hi2(u);
        }
      }
      float S = ((Sc[0] + Sc[1]) + (Sc[2] + Sc[3])) + ((Sc[4] + Sc[5]) + (Sc[6] + Sc[7]));
      float SS = ((SSc[0] + SSc[1]) + (SSc[2] + SSc[3])) + ((SSc[4] + SSc[5]) + (SSc[6] + SSc[7]));
      float mu = S * (1.f / 512.f);
      float var = SS * (1.f / 512.f) - mu * mu;
      minv[tid * 2 + 0] = mu;
      minv[tid * 2 + 1] = rsqrtf(fmaxf(var, 0.f) + 1e-5f);
    }
    __syncthreads();

    // normalize + cell (thread owns (srow, hc))
    {
      float gv[4];
#pragma unroll
      for (int g = 0; g < 4; ++g) {
        float pre = gates[srow * 16 + g * 4 + sg];
        gv[g] = (pre - minv[(srow * 4 + g) * 2]) * minv[(srow * 4 + g) * 2 + 1] * gam[g] + bet[g];
      }
      float ig = sigm(gv[0]);
      float fg = sigm(gv[1]);
      float og = sigm(gv[2]);
      float ug = tanh_f(gv[3]);
      c_st = fg * c_st + ig * ug;
      float hv = og * tanh_f(c_st);

      // pair-pack (even sg stores {sg, sg+1}) and SYSTEM-store h and y
      float hv2 = __shfl_down(hv, 1);
      float cv2 = __shfl_down(c_st, 1);
      if ((sg & 1) == 0) {
        unsigned long long hp = pack2(hv, hv2);
        sys_store64((unsigned long long*)&hstL[srow * 512 + hc], hp);
        sys_store64((unsigned long long*)&out[(size_t)t * 32768 + srow * 512 + hc], hp);
        if (t == 511) {
          sys_store64((unsigned long long*)&out[16777216 + layer * 32768 + srow * 512 + hc], hp);
          sys_store64((unsigned long long*)&out[16842752 + layer * 32768 + srow * 512 + hc],
                      pack2(c_st, cv2));
        }
      }
    }
    post(myflag, t2 + 2u);               // h / y0 posted
  }
}

extern "C" void kernel_launch(void* const* d_in, const int* in_sizes, int n_in,
                              void* d_out, int out_size, void* d_ws, size_t ws_size,
                              hipStream_t stream) {
  const float* inputs = (const float*)d_in[0];
  const float* h0 = (const float*)d_in[1];
  const float* c0 = (const float*)d_in[2];
  const float* wx0 = (const float*)d_in[3];
  const float* wx1 = (const float*)d_in[4];
  const float* wh0 = (const float*)d_in[5];
  const float* wh1 = (const float*)d_in[6];
  const float* bias = (const float*)d_in[7];
  const float* gamma_ = (const float*)d_in[8];
  const float* beta_ = (const float*)d_in[9];
  float* out = (float*)d_out;

  char* ws = (char*)d_ws;
  unsigned int* flags = (unsigned int*)ws;                       // 32 KB used (64K pad)
  unsigned long long* slots = (unsigned long long*)(ws + 65536); // 512 KB
  float* h_state = (float*)(ws + 65536 + 524288);                // 256 KB

  const int smem_bytes = 158720;
  hipFuncSetAttribute((const void*)lstm_pk,
                      hipFuncAttributeMaxDynamicSharedMemorySize, smem_bytes);
  hipMemsetAsync(ws, 0, 65536, stream);           // zero flags

  hipLaunchKernelGGL(lstm_pk, dim3(256), dim3(NTH), smem_bytes, stream,
                     inputs, h0, c0, wx0, wx1, wh0, wh1, bias, gamma_, beta_,
                     out, flags, slots, h_state);
}